// Round 12
// baseline (160.040 us; speedup 1.0000x reference)
//
#include <hip/hip_runtime.h>
#include <hip/hip_bf16.h>

#define HB_ELEMS ((size_t)1024 * 2048)   // elements in one H x B output
#define P_ELEMS  ((size_t)4096 * 2048)   // one split-K partial

typedef __bf16 bfx8 __attribute__((ext_vector_type(8)));
typedef float f32x4 __attribute__((ext_vector_type(4)));

__device__ __forceinline__ float b2f(unsigned short u) {
    union { unsigned int i; float f; } v; v.i = ((unsigned int)u) << 16; return v.f;
}
__device__ __forceinline__ unsigned short f2b(float f) {
    __hip_bfloat16 h = __float2bfloat16(f);
    return *reinterpret_cast<unsigned short*>(&h);
}
__device__ __forceinline__ float loadf(const void* p, size_t i, bool f32) {
    return f32 ? ((const float*)p)[i] : b2f(((const unsigned short*)p)[i]);
}
__device__ __forceinline__ float sigf(float x) { return 1.0f / (1.0f + __expf(-x)); }

__device__ __forceinline__ void cell_math(float fp, float ip, float op, float gp,
                                           float cc, float hh, float zc, float zv,
                                           float& hn, float& cn) {
    float f = sigf(fp), i = sigf(ip), o = sigf(op), g = tanhf(gp);
    float ig = i * g;
    cn = zc * ig + (1.0f - zc) * (1.0f - zv) * cc + (1.0f - zc) * zv * (f * cc + ig);
    float tc = tanhf(cn);
    hn = zc * o * tc + (1.0f - zc) * (1.0f - zv) * hh + (1.0f - zc) * zv * o * tc;
}

// ---------------------------------------------------------------------------
// dtype detector (1 wave)
// ---------------------------------------------------------------------------
__global__ void detect_k(const unsigned short* __restrict__ w, int* __restrict__ flag) {
    int lane = threadIdx.x;
    bool hit = false;
    #pragma unroll
    for (int i = 0; i < 4; ++i) {
        unsigned e = (w[lane + i * 64] >> 7) & 0xFF;
        hit |= (e >= 126);
    }
    unsigned long long m = __ballot(hit);
    if (lane == 0) *flag = (m != 0ULL) ? 1 : 0;
}

// ---------------------------------------------------------------------------
// BT[b][k] = [h_bottom; z*h; z*h_top]^T  (2048 x 3072 bf16)
// ---------------------------------------------------------------------------
__global__ __launch_bounds__(256) void build_bt(
    const void* __restrict__ hb, const void* __restrict__ h,
    const void* __restrict__ ht, const void* __restrict__ z,
    unsigned short* __restrict__ BT, const int* __restrict__ flagp)
{
    const bool f32 = (*flagp != 0);
    int tid = blockIdx.x * 256 + threadIdx.x;
    int b   = tid & 2047;
    int kg8 = tid >> 11;            // 0..383
    int k   = kg8 * 8;

    const void* src; int kl; bool sc;
    if (k < 1024)      { src = hb; kl = k;        sc = false; }
    else if (k < 2048) { src = h;  kl = k - 1024; sc = true;  }
    else               { src = ht; kl = k - 2048; sc = true;  }

    bool zero = sc && (loadf(z, b, f32) == 0.0f);   // z is exactly 0.0 or 1.0
    unsigned short t[8];
    if (zero) {
        #pragma unroll
        for (int j = 0; j < 8; ++j) t[j] = 0;
    } else if (f32) {
        #pragma unroll
        for (int j = 0; j < 8; ++j) t[j] = f2b(((const float*)src)[(size_t)(kl + j) * 2048 + b]);
    } else {
        #pragma unroll
        for (int j = 0; j < 8; ++j) t[j] = ((const unsigned short*)src)[(size_t)(kl + j) * 2048 + b];
    }
    uint4 v;
    v.x = (unsigned)t[0] | ((unsigned)t[1] << 16);
    v.y = (unsigned)t[2] | ((unsigned)t[3] << 16);
    v.z = (unsigned)t[4] | ((unsigned)t[5] << 16);
    v.w = (unsigned)t[6] | ((unsigned)t[7] << 16);
    *reinterpret_cast<uint4*>(&BT[(size_t)b * 3072 + k]) = v;
}

// ---------------------------------------------------------------------------
// Split-K GEMM, 256x256 tile, 8 waves (2M x 4N), BK=64, dbuf LDS (128 KB),
// m201-style 4-PHASE schedule per K-tile:
//   stage(8 loads, t+1) -> vmcnt(8) -> [SB s_barrier SB]
//   phase q in 0..3: { ds_read quadrant -> lgkmcnt(0)+SB ->
//                      setprio(1) 16 MFMA setprio(0) -> [SB s_barrier SB] }
// Quadrant = (kk = q>>1, mi-half = q&1); bv reused across mi-half phases.
// T2 XOR-swizzle (conflicts=0, r8). Grid 8x16x2 = 256 blocks = 1/CU.
// Buffer safety: q3's barrier orders all buf[cur] reads before t+1's stage
// overwrites it; per-phase fenced barriers prevent cross-phase code motion.
// ---------------------------------------------------------------------------
__global__ __launch_bounds__(512, 1) void gemm_split(
    const void* __restrict__ Whh, const void* __restrict__ U11, const void* __restrict__ U21,
    const unsigned short* __restrict__ BT,
    unsigned short* __restrict__ P, const int* __restrict__ flagp)
{
    const bool f32 = (*flagp != 0);
    __shared__ __align__(16) unsigned short As[2][256 * 64];   // 64 KB
    __shared__ __align__(16) unsigned short Bs[2][256 * 64];   // 64 KB

    // ---- XCD swizzle: 256 blocks; 32 contiguous sids per XCD
    int id  = (blockIdx.z * 16 + blockIdx.y) * 8 + blockIdx.x;
    int sid = (id & 7) * 32 + (id >> 3);
    const int n0   = (sid & 7) * 256;          // N tile
    const int j0   = ((sid >> 3) & 15) * 64;   // 64 j's per M tile
    const int kseg = sid >> 7;                 // 0..1
    const int kbase = kseg * 1536;

    const int wave = threadIdx.x >> 6;         // 0..7
    const int lane = threadIdx.x & 63;
    // T2: pre-swizzled global source chunk; linear gload_lds dest then holds
    // LDS(row, c) = global chunk c ^ (row&7), with row&7 == lane>>3.
    const int scol_sw = (((lane & 7) ^ (lane >> 3)) * 8);
    const int wm = wave >> 2, wn = wave & 3;
    const int lr = lane & 15, kg = lane >> 4;
    const int lr7 = lr & 7;

    f32x4 acc[8][4] = {};

    auto stage = [&](int buf, int kt) {
        const int kglob = kbase + kt * 64;
        const int seg = kglob >> 10, kl = kglob & 1023;
        const void* Ap = (seg == 0) ? Whh : ((seg == 1) ? U11 : U21);

        #pragma unroll
        for (int r = 0; r < 4; ++r) {
            int trow = r * 64 + wave * 8 + (lane >> 3);          // 0..255
            const unsigned short* g = &BT[(size_t)(n0 + trow) * 3072 + kglob + scol_sw];
            __builtin_amdgcn_global_load_lds(
                (const __attribute__((address_space(1))) void*)g,
                (__attribute__((address_space(3))) void*)((char*)&Bs[buf][0] + r * 8192 + wave * 1024),
                16, 0, 0);
        }
        if (!f32) {
            #pragma unroll
            for (int r = 0; r < 4; ++r) {
                int trow = r * 64 + wave * 8 + (lane >> 3);
                size_t arow = (size_t)((trow >> 6) * 1024 + j0 + (trow & 63));
                const unsigned short* g = (const unsigned short*)Ap + arow * 1024 + kl + scol_sw;
                __builtin_amdgcn_global_load_lds(
                    (const __attribute__((address_space(1))) void*)g,
                    (__attribute__((address_space(3))) void*)((char*)&As[buf][0] + r * 8192 + wave * 1024),
                    16, 0, 0);
            }
        } else {
            // reg-staged: linear global chunk, ds_write to swizzled chunk
            #pragma unroll
            for (int r = 0; r < 4; ++r) {
                int trow = r * 64 + wave * 8 + (lane >> 3);
                size_t arow = (size_t)((trow >> 6) * 1024 + j0 + (trow & 63));
                const float* g = (const float*)Ap + arow * 1024 + kl + (lane & 7) * 8;
                float4 a0 = *reinterpret_cast<const float4*>(g);
                float4 a1 = *reinterpret_cast<const float4*>(g + 4);
                uint4 v;
                v.x = (unsigned)f2b(a0.x) | ((unsigned)f2b(a0.y) << 16);
                v.y = (unsigned)f2b(a0.z) | ((unsigned)f2b(a0.w) << 16);
                v.z = (unsigned)f2b(a1.x) | ((unsigned)f2b(a1.y) << 16);
                v.w = (unsigned)f2b(a1.z) | ((unsigned)f2b(a1.w) << 16);
                *reinterpret_cast<uint4*>(&As[buf][trow * 64 + scol_sw]) = v;
            }
        }
    };

    stage(0, 0);    // prologue: tile 0's 8 loads in flight

    for (int kt = 0; kt < 24; ++kt) {
        const int cur = kt & 1;
        unsigned short* Acur = &As[cur][0];
        unsigned short* Bcur = &Bs[cur][0];

        if (kt < 23) stage(cur ^ 1, kt + 1);    // next tile's 8 loads fly over this tile

        if (f32) {
            asm volatile("s_waitcnt vmcnt(0) lgkmcnt(0)" ::: "memory");
        } else if (kt < 23) {
            asm volatile("s_waitcnt vmcnt(8)" ::: "memory");
        } else {
            asm volatile("s_waitcnt vmcnt(0)" ::: "memory");
        }
        __builtin_amdgcn_sched_barrier(0);
        __builtin_amdgcn_s_barrier();           // tile kt landed, visible to all waves
        __builtin_amdgcn_sched_barrier(0);

        bfx8 bv[4];
        #pragma unroll
        for (int ph = 0; ph < 4; ++ph) {
            const int kk = ph >> 1;             // 0,0,1,1
            const int mh = ph & 1;              // 0,1,0,1
            const int csw = ((kk * 4 + kg) ^ lr7) * 8;

            if (mh == 0) {
                #pragma unroll
                for (int ni = 0; ni < 4; ++ni)
                    bv[ni] = *reinterpret_cast<const bfx8*>(
                        &Bcur[(wn * 64 + ni * 16 + lr) * 64 + csw]);
            }
            bfx8 av[4];
            #pragma unroll
            for (int mi = 0; mi < 4; ++mi)
                av[mi] = *reinterpret_cast<const bfx8*>(
                    &Acur[(wm * 128 + (mh * 4 + mi) * 16 + lr) * 64 + csw]);

            asm volatile("s_waitcnt lgkmcnt(0)" ::: "memory");
            __builtin_amdgcn_sched_barrier(0);
            __builtin_amdgcn_s_setprio(1);
            #pragma unroll
            for (int mi = 0; mi < 4; ++mi)
                #pragma unroll
                for (int ni = 0; ni < 4; ++ni)
                    acc[mh * 4 + mi][ni] = __builtin_amdgcn_mfma_f32_16x16x32_bf16(
                        av[mi], bv[ni], acc[mh * 4 + mi][ni], 0, 0, 0);
            __builtin_amdgcn_s_setprio(0);
            __builtin_amdgcn_sched_barrier(0);
            __builtin_amdgcn_s_barrier();       // phase-lock; q3's instance guards buf flip
            __builtin_amdgcn_sched_barrier(0);
        }
    }

    // Write bf16 partials. C/D layout: col = lane&15, row = kg*4 + r [m89].
    unsigned short* Pp = P + (size_t)kseg * P_ELEMS;
    #pragma unroll
    for (int mi = 0; mi < 8; ++mi) {
        #pragma unroll
        for (int ni = 0; ni < 4; ++ni) {
            int col = n0 + wn * 64 + ni * 16 + lr;
            #pragma unroll
            for (int r = 0; r < 4; ++r) {
                int trow = wm * 128 + mi * 16 + kg * 4 + r;   // 0..255
                int gate = trow >> 6, jj = trow & 63;
                size_t m = (size_t)gate * 1024 + j0 + jj;
                Pp[m * 2048 + col] = f2b(acc[mi][ni][r]);
            }
        }
    }
}

// ---------------------------------------------------------------------------
// Epilogue: sum 2 bf16 partials per gate, bias, cell math, stores.
// ---------------------------------------------------------------------------
__global__ __launch_bounds__(256) void epilogue_split(
    const unsigned short* __restrict__ P, const void* __restrict__ c_,
    const void* __restrict__ h_, const void* __restrict__ z_,
    const void* __restrict__ zb_, const void* __restrict__ bias_,
    void* __restrict__ out_, const int* __restrict__ flagp)
{
    const bool f32 = (*flagp != 0);
    int tid = blockIdx.x * 256 + threadIdx.x;       // 0 .. 1024*512-1
    int j = tid >> 9;
    int b = (tid & 511) << 2;
    const size_t jb = (size_t)j * 2048 + b;

    float pre[4][4];
    #pragma unroll
    for (int g = 0; g < 4; ++g) {
        size_t row = (size_t)(g * 1024 + j) * 2048 + b;
        ushort4 s0 = *reinterpret_cast<const ushort4*>(&P[row]);
        ushort4 s1 = *reinterpret_cast<const ushort4*>(&P[P_ELEMS + row]);
        float bv = loadf(bias_, g * 1024 + j, f32);
        pre[g][0] = b2f(s0.x) + b2f(s1.x) + bv;
        pre[g][1] = b2f(s0.y) + b2f(s1.y) + bv;
        pre[g][2] = b2f(s0.z) + b2f(s1.z) + bv;
        pre[g][3] = b2f(s0.w) + b2f(s1.w) + bv;
    }

    float hn[4], cn[4];
    #pragma unroll
    for (int e = 0; e < 4; ++e) {
        float zc = loadf(z_, b + e, f32);
        float zv = loadf(zb_, b + e, f32);
        float cc = loadf(c_, jb + e, f32);
        float hh = loadf(h_, jb + e, f32);
        cell_math(pre[0][e], pre[1][e], pre[2][e], pre[3][e], cc, hh, zc, zv, hn[e], cn[e]);
    }
    if (f32) {
        float4 ho = {hn[0], hn[1], hn[2], hn[3]};
        float4 co = {cn[0], cn[1], cn[2], cn[3]};
        *reinterpret_cast<float4*>(&((float*)out_)[jb]) = ho;
        *reinterpret_cast<float4*>(&((float*)out_)[HB_ELEMS + jb]) = co;
    } else {
        ushort4 ho = {f2b(hn[0]), f2b(hn[1]), f2b(hn[2]), f2b(hn[3])};
        ushort4 co = {f2b(cn[0]), f2b(cn[1]), f2b(cn[2]), f2b(cn[3])};
        *reinterpret_cast<ushort4*>(&((unsigned short*)out_)[jb]) = ho;
        *reinterpret_cast<ushort4*>(&((unsigned short*)out_)[HB_ELEMS + jb]) = co;
    }
}

// ---------------------------------------------------------------------------
// Single-pass fused GEMM (fallback when ws too small for split-K partials)
// ---------------------------------------------------------------------------
__global__ __launch_bounds__(256) void gemm_fused(
    const void* __restrict__ Whh, const void* __restrict__ U11, const void* __restrict__ U21,
    const unsigned short* __restrict__ BT,
    const void* __restrict__ c_, const void* __restrict__ h_,
    const void* __restrict__ z_, const void* __restrict__ zb_,
    const void* __restrict__ bias_, void* __restrict__ out_,
    const int* __restrict__ flagp)
{
    const bool f32 = (*flagp != 0);
    __shared__ __align__(16) unsigned short As[128 * 64];
    __shared__ __align__(16) unsigned short Bs[128 * 64];

    const int n0 = blockIdx.x * 128;
    const int j0 = blockIdx.y * 32;
    const int wave = threadIdx.x >> 6;
    const int lane = threadIdx.x & 63;
    const int srow = wave * 8 + (lane >> 3);
    const int scol = (lane & 7) * 8;
    const int lr = lane & 15, kg = lane >> 4;

    f32x4 acc[8][2] = {};

    for (int k0 = 0; k0 < 3072; k0 += 64) {
        int seg = k0 >> 10, kl = k0 & 1023;
        const void* Asrc = (seg == 0) ? Whh : ((seg == 1) ? U11 : U21);

        __syncthreads();
        #pragma unroll
        for (int r = 0; r < 4; ++r) {
            const unsigned short* g = &BT[(size_t)(n0 + r * 32 + srow) * 3072 + k0 + scol];
            __builtin_amdgcn_global_load_lds(
                (const __attribute__((address_space(1))) void*)g,
                (__attribute__((address_space(3))) void*)((char*)Bs + r * 4096 + wave * 1024),
                16, 0, 0);
        }
        if (!f32) {
            #pragma unroll
            for (int r = 0; r < 4; ++r) {
                const unsigned short* g = (const unsigned short*)Asrc
                    + (size_t)(r * 1024 + j0 + srow) * 1024 + kl + scol;
                __builtin_amdgcn_global_load_lds(
                    (const __attribute__((address_space(1))) void*)g,
                    (__attribute__((address_space(3))) void*)((char*)As + r * 4096 + wave * 1024),
                    16, 0, 0);
            }
        } else {
            #pragma unroll
            for (int r = 0; r < 4; ++r) {
                int trow = r * 32 + srow;
                const float* g = (const float*)Asrc + (size_t)(r * 1024 + j0 + srow) * 1024 + kl + scol;
                float4 a0 = *reinterpret_cast<const float4*>(g);
                float4 a1 = *reinterpret_cast<const float4*>(g + 4);
                uint4 v;
                v.x = (unsigned)f2b(a0.x) | ((unsigned)f2b(a0.y) << 16);
                v.y = (unsigned)f2b(a0.z) | ((unsigned)f2b(a0.w) << 16);
                v.z = (unsigned)f2b(a1.x) | ((unsigned)f2b(a1.y) << 16);
                v.w = (unsigned)f2b(a1.z) | ((unsigned)f2b(a1.w) << 16);
                *reinterpret_cast<uint4*>(&As[trow * 64 + scol]) = v;
            }
        }
        __syncthreads();

        #pragma unroll
        for (int kk = 0; kk < 64; kk += 32) {
            bfx8 bv0 = *reinterpret_cast<const bfx8*>(&Bs[(wave * 32 + lr) * 64 + kk + kg * 8]);
            bfx8 bv1 = *reinterpret_cast<const bfx8*>(&Bs[(wave * 32 + 16 + lr) * 64 + kk + kg * 8]);
            #pragma unroll
            for (int mi = 0; mi < 8; ++mi) {
                bfx8 af = *reinterpret_cast<const bfx8*>(&As[(mi * 16 + lr) * 64 + kk + kg * 8]);
                acc[mi][0] = __builtin_amdgcn_mfma_f32_16x16x32_bf16(af, bv0, acc[mi][0], 0, 0, 0);
                acc[mi][1] = __builtin_amdgcn_mfma_f32_16x16x32_bf16(af, bv1, acc[mi][1], 0, 0, 0);
            }
        }
    }

    #pragma unroll
    for (int ni = 0; ni < 2; ++ni) {
        int b = n0 + wave * 32 + ni * 16 + lr;
        float zc = loadf(z_, b, f32);
        float zv = loadf(zb_, b, f32);
        #pragma unroll
        for (int mh = 0; mh < 2; ++mh) {
            #pragma unroll
            for (int r = 0; r < 4; ++r) {
                int j = j0 + mh * 16 + kg * 4 + r;
                float fp = acc[0 + mh][ni][r] + loadf(bias_, j, f32);
                float ip = acc[2 + mh][ni][r] + loadf(bias_, 1024 + j, f32);
                float op = acc[4 + mh][ni][r] + loadf(bias_, 2048 + j, f32);
                float gp = acc[6 + mh][ni][r] + loadf(bias_, 3072 + j, f32);
                float cc = loadf(c_, (size_t)j * 2048 + b, f32);
                float hh = loadf(h_, (size_t)j * 2048 + b, f32);
                float hn, cn;
                cell_math(fp, ip, op, gp, cc, hh, zc, zv, hn, cn);
                if (f32) {
                    ((float*)out_)[(size_t)j * 2048 + b] = hn;
                    ((float*)out_)[HB_ELEMS + (size_t)j * 2048 + b] = cn;
                } else {
                    ((unsigned short*)out_)[(size_t)j * 2048 + b] = f2b(hn);
                    ((unsigned short*)out_)[HB_ELEMS + (size_t)j * 2048 + b] = f2b(cn);
                }
            }
        }
    }
}

// ---------------------------------------------------------------------------
// z-row partials + reduce
// ---------------------------------------------------------------------------
__global__ __launch_bounds__(256) void zrow_part(
    const void* __restrict__ Whh, const void* __restrict__ U11, const void* __restrict__ U21,
    const void* __restrict__ hb, const void* __restrict__ h, const void* __restrict__ ht,
    float* __restrict__ pz, const int* __restrict__ flagp)
{
    const bool f32 = (*flagp != 0);
    const int c   = blockIdx.x;          // 0..95
    const int mat = c >> 5;              // 0..2
    const int k0  = (c & 31) * 32;
    const int b0  = threadIdx.x * 8;

    const void* W = (mat == 0) ? Whh : ((mat == 1) ? U11 : U21);
    const void* X = (mat == 0) ? hb  : ((mat == 1) ? h   : ht);
    const size_t wrow = (size_t)4096 * 1024;

    float acc[8] = {0.f, 0.f, 0.f, 0.f, 0.f, 0.f, 0.f, 0.f};
    if (!f32) {
        const unsigned short* Wp = (const unsigned short*)W;
        const unsigned short* Xp = (const unsigned short*)X;
        #pragma unroll 4
        for (int kk = 0; kk < 32; ++kk) {
            int k = k0 + kk;
            float w = b2f(Wp[wrow + k]);
            ushort4 xa = *reinterpret_cast<const ushort4*>(&Xp[(size_t)k * 2048 + b0]);
            ushort4 xb = *reinterpret_cast<const ushort4*>(&Xp[(size_t)k * 2048 + b0 + 4]);
            acc[0] += w * b2f(xa.x); acc[1] += w * b2f(xa.y);
            acc[2] += w * b2f(xa.z); acc[3] += w * b2f(xa.w);
            acc[4] += w * b2f(xb.x); acc[5] += w * b2f(xb.y);
            acc[6] += w * b2f(xb.z); acc[7] += w * b2f(xb.w);
        }
    } else {
        const float* Wp = (const float*)W;
        const float* Xp = (const float*)X;
        #pragma unroll 4
        for (int kk = 0; kk < 32; ++kk) {
            int k = k0 + kk;
            float w = Wp[wrow + k];
            float4 xa = *reinterpret_cast<const float4*>(&Xp[(size_t)k * 2048 + b0]);
            float4 xb = *reinterpret_cast<const float4*>(&Xp[(size_t)k * 2048 + b0 + 4]);
            acc[0] += w * xa.x; acc[1] += w * xa.y; acc[2] += w * xa.z; acc[3] += w * xa.w;
            acc[4] += w * xb.x; acc[5] += w * xb.y; acc[6] += w * xb.z; acc[7] += w * xb.w;
        }
    }
    #pragma unroll
    for (int j = 0; j < 8; ++j)
        pz[(size_t)c * 2048 + b0 + j] = acc[j];
}

__global__ __launch_bounds__(256) void zrow_reduce(
    const float* __restrict__ pz, const void* __restrict__ z_,
    const void* __restrict__ bias_, void* __restrict__ out_,
    const int* __restrict__ flagp)
{
    const bool f32 = (*flagp != 0);
    int b = blockIdx.x * 256 + threadIdx.x;
    float a1 = 0.f, a2 = 0.f, a3 = 0.f;
    #pragma unroll
    for (int c = 0; c < 32; ++c)  a1 += pz[(size_t)c * 2048 + b];
    #pragma unroll
    for (int c = 32; c < 64; ++c) a2 += pz[(size_t)c * 2048 + b];
    #pragma unroll
    for (int c = 64; c < 96; ++c) a3 += pz[(size_t)c * 2048 + b];
    float zc = loadf(z_, b, f32);
    float s = a1 + zc * (a2 + a3) + loadf(bias_, 4096, f32);
    float zh = (s + 1.0f) * 0.5f;
    zh = fminf(fmaxf(zh, 0.0f), 1.0f);
    float zn = (zh > 0.5f) ? 1.0f : 0.0f;
    if (f32) ((float*)out_)[2 * HB_ELEMS + b] = zn;
    else     ((unsigned short*)out_)[2 * HB_ELEMS + b] = f2b(zn);
}

__global__ __launch_bounds__(256) void zrow_k(
    const void* __restrict__ Whh, const void* __restrict__ U11, const void* __restrict__ U21,
    const void* __restrict__ hb, const void* __restrict__ h, const void* __restrict__ ht,
    const void* __restrict__ z_, const void* __restrict__ bias_,
    void* __restrict__ out_, const int* __restrict__ flagp)
{
    const bool f32 = (*flagp != 0);
    int b = blockIdx.x * 256 + threadIdx.x;
    float a1 = 0.f, a2 = 0.f, a3 = 0.f;
    const size_t wrow = (size_t)4096 * 1024;
    for (int k = 0; k < 1024; ++k) {
        a1 += loadf(Whh, wrow + k, f32) * loadf(hb, (size_t)k * 2048 + b, f32);
        a2 += loadf(U11, wrow + k, f32) * loadf(h,  (size_t)k * 2048 + b, f32);
        a3 += loadf(U21, wrow + k, f32) * loadf(ht, (size_t)k * 2048 + b, f32);
    }
    float zc = loadf(z_, b, f32);
    float s = a1 + zc * (a2 + a3) + loadf(bias_, 4096, f32);
    float zh = (s + 1.0f) * 0.5f;
    zh = fminf(fmaxf(zh, 0.0f), 1.0f);
    float zn = (zh > 0.5f) ? 1.0f : 0.0f;
    if (f32) ((float*)out_)[2 * HB_ELEMS + b] = zn;
    else     ((unsigned short*)out_)[2 * HB_ELEMS + b] = f2b(zn);
}

// ---------------------------------------------------------------------------
// Fallback full cell (tiny ws)
// ---------------------------------------------------------------------------
__global__ __launch_bounds__(256) void fallback_k(
    const void* __restrict__ Whh, const void* __restrict__ U11, const void* __restrict__ U21,
    const void* __restrict__ hb, const void* __restrict__ h, const void* __restrict__ ht,
    const void* __restrict__ c_, const void* __restrict__ z_, const void* __restrict__ zb_,
    const void* __restrict__ bias_, void* __restrict__ out_, const int* __restrict__ flagp)
{
    const bool f32 = (*flagp != 0);
    int b = blockIdx.x * 256 + threadIdx.x;
    int j = blockIdx.y;
    float zc = loadf(z_, b, f32);
    float a[4] = {0.f, 0.f, 0.f, 0.f};
    for (int k = 0; k < 1024; ++k) {
        float xb = loadf(hb, (size_t)k * 2048 + b, f32);
        #pragma unroll
        for (int g = 0; g < 4; ++g)
            a[g] += loadf(Whh, (size_t)(g * 1024 + j) * 1024 + k, f32) * xb;
    }
    for (int k = 0; k < 1024; ++k) {
        float xh = zc * loadf(h, (size_t)k * 2048 + b, f32);
        #pragma unroll
        for (int g = 0; g < 4; ++g)
            a[g] += loadf(U11, (size_t)(g * 1024 + j) * 1024 + k, f32) * xh;
    }
    for (int k = 0; k < 1024; ++k) {
        float xt = zc * loadf(ht, (size_t)k * 2048 + b, f32);
        #pragma unroll
        for (int g = 0; g < 4; ++g)
            a[g] += loadf(U21, (size_t)(g * 1024 + j) * 1024 + k, f32) * xt;
    }
    float fp = a[0] + loadf(bias_, j, f32);
    float ip = a[1] + loadf(bias_, 1024 + j, f32);
    float op = a[2] + loadf(bias_, 2048 + j, f32);
    float gp = a[3] + loadf(bias_, 3072 + j, f32);
    float cc = loadf(c_, (size_t)j * 2048 + b, f32);
    float hh = loadf(h,  (size_t)j * 2048 + b, f32);
    float zv = loadf(zb_, b, f32);
    float hn, cn;
    cell_math(fp, ip, op, gp, cc, hh, zc, zv, hn, cn);
    if (f32) {
        ((float*)out_)[(size_t)j * 2048 + b] = hn;
        ((float*)out_)[HB_ELEMS + (size_t)j * 2048 + b] = cn;
    } else {
        ((unsigned short*)out_)[(size_t)j * 2048 + b] = f2b(hn);
        ((unsigned short*)out_)[HB_ELEMS + (size_t)j * 2048 + b] = f2b(cn);
    }
}

// ---------------------------------------------------------------------------
extern "C" void kernel_launch(void* const* d_in, const int* in_sizes, int n_in,
                              void* d_out, int out_size, void* d_ws, size_t ws_size,
                              hipStream_t stream)
{
    // setup_inputs order: c, h_bottom, h, h_top, z, z_bottom, W_hh, U_11, U_21, bias
    const void* c    = d_in[0];
    const void* hb   = d_in[1];
    const void* h    = d_in[2];
    const void* ht   = d_in[3];
    const void* z    = d_in[4];
    const void* zb   = d_in[5];
    const void* Whh  = d_in[6];
    const void* U11  = d_in[7];
    const void* U21  = d_in[8];
    const void* bias = d_in[9];

    int* flag = (int*)d_ws;
    unsigned short* BT = (unsigned short*)((char*)d_ws + 4096);
    const size_t bt_bytes = (size_t)2048 * 3072 * 2;                 // 12.58 MB
    float* pz = (float*)((char*)d_ws + 4096 + bt_bytes);
    const size_t pz_bytes = (size_t)96 * 2048 * 4;                   // 768 KB
    unsigned short* P = (unsigned short*)((char*)d_ws + 4096 + bt_bytes + pz_bytes);
    const size_t p_bytes = 2 * P_ELEMS * 2;                          // 33.55 MB (bf16, splitK=2)

    const size_t need_bt    = 4096 + bt_bytes;
    const size_t need_pz    = need_bt + pz_bytes;
    const size_t need_split = need_pz + p_bytes;                     // ~46.9 MB

    if (ws_size < 4) return;

    detect_k<<<1, 64, 0, stream>>>((const unsigned short*)Whh, flag);

    if (ws_size >= need_split) {
        build_bt<<<(2048 * 384) / 256, 256, 0, stream>>>(hb, h, ht, z, BT, flag);
        gemm_split<<<dim3(8, 16, 2), 512, 0, stream>>>(Whh, U11, U21, BT, P, flag);
        epilogue_split<<<(1024 * 512) / 256, 256, 0, stream>>>(P, c, h, z, zb, bias, d_out, flag);
    } else if (ws_size >= need_bt) {
        build_bt<<<(2048 * 384) / 256, 256, 0, stream>>>(hb, h, ht, z, BT, flag);
        gemm_fused<<<dim3(16, 32), 256, 0, stream>>>(Whh, U11, U21, BT,
                                                     c, h, z, zb, bias, d_out, flag);
    } else {
        fallback_k<<<dim3(8, 1024), 256, 0, stream>>>(Whh, U11, U21, hb, h, ht,
                                                      c, z, zb, bias, d_out, flag);
    }

    if (ws_size >= need_pz) {
        zrow_part<<<96, 256, 0, stream>>>(Whh, U11, U21, hb, h, ht, pz, flag);
        zrow_reduce<<<8, 256, 0, stream>>>(pz, z, bias, d_out, flag);
    } else {
        zrow_k<<<8, 256, 0, stream>>>(Whh, U11, U21, hb, h, ht, z, bias, d_out, flag);
    }
}

// Round 13
// 133.940 us; speedup vs baseline: 1.1949x; 1.1949x over previous
//
#include <hip/hip_runtime.h>
#include <hip/hip_bf16.h>

#define HB_ELEMS ((size_t)1024 * 2048)   // elements in one H x B output
#define P_ELEMS  ((size_t)4096 * 2048)   // one split-K partial

typedef __bf16 bfx8 __attribute__((ext_vector_type(8)));
typedef float f32x4 __attribute__((ext_vector_type(4)));

__device__ __forceinline__ float b2f(unsigned short u) {
    union { unsigned int i; float f; } v; v.i = ((unsigned int)u) << 16; return v.f;
}
__device__ __forceinline__ unsigned short f2b(float f) {
    __hip_bfloat16 h = __float2bfloat16(f);
    return *reinterpret_cast<unsigned short*>(&h);
}
__device__ __forceinline__ float loadf(const void* p, size_t i, bool f32) {
    return f32 ? ((const float*)p)[i] : b2f(((const unsigned short*)p)[i]);
}
__device__ __forceinline__ float sigf(float x) { return 1.0f / (1.0f + __expf(-x)); }

__device__ __forceinline__ void cell_math(float fp, float ip, float op, float gp,
                                           float cc, float hh, float zc, float zv,
                                           float& hn, float& cn) {
    float f = sigf(fp), i = sigf(ip), o = sigf(op), g = tanhf(gp);
    float ig = i * g;
    cn = zc * ig + (1.0f - zc) * (1.0f - zv) * cc + (1.0f - zc) * zv * (f * cc + ig);
    float tc = tanhf(cn);
    hn = zc * o * tc + (1.0f - zc) * (1.0f - zv) * hh + (1.0f - zc) * zv * o * tc;
}

// ---------------------------------------------------------------------------
// dtype detector (1 wave)
// ---------------------------------------------------------------------------
__global__ void detect_k(const unsigned short* __restrict__ w, int* __restrict__ flag) {
    int lane = threadIdx.x;
    bool hit = false;
    #pragma unroll
    for (int i = 0; i < 4; ++i) {
        unsigned e = (w[lane + i * 64] >> 7) & 0xFF;
        hit |= (e >= 126);
    }
    unsigned long long m = __ballot(hit);
    if (lane == 0) *flag = (m != 0ULL) ? 1 : 0;
}

// ---------------------------------------------------------------------------
// device bodies (shared by merged + standalone kernels)
// ---------------------------------------------------------------------------
__device__ __forceinline__ void dev_build_bt(
    int tid, const void* hb, const void* h, const void* ht, const void* z,
    unsigned short* BT, bool f32)
{
    int b   = tid & 2047;
    int kg8 = tid >> 11;            // 0..383
    int k   = kg8 * 8;

    const void* src; int kl; bool sc;
    if (k < 1024)      { src = hb; kl = k;        sc = false; }
    else if (k < 2048) { src = h;  kl = k - 1024; sc = true;  }
    else               { src = ht; kl = k - 2048; sc = true;  }

    bool zero = sc && (loadf(z, b, f32) == 0.0f);   // z is exactly 0.0 or 1.0
    unsigned short t[8];
    if (zero) {
        #pragma unroll
        for (int j = 0; j < 8; ++j) t[j] = 0;
    } else if (f32) {
        #pragma unroll
        for (int j = 0; j < 8; ++j) t[j] = f2b(((const float*)src)[(size_t)(kl + j) * 2048 + b]);
    } else {
        #pragma unroll
        for (int j = 0; j < 8; ++j) t[j] = ((const unsigned short*)src)[(size_t)(kl + j) * 2048 + b];
    }
    uint4 v;
    v.x = (unsigned)t[0] | ((unsigned)t[1] << 16);
    v.y = (unsigned)t[2] | ((unsigned)t[3] << 16);
    v.z = (unsigned)t[4] | ((unsigned)t[5] << 16);
    v.w = (unsigned)t[6] | ((unsigned)t[7] << 16);
    *reinterpret_cast<uint4*>(&BT[(size_t)b * 3072 + k]) = v;
}

__device__ __forceinline__ void dev_zrow_part(
    int c, int t, const void* Whh, const void* U11, const void* U21,
    const void* hb, const void* h, const void* ht, float* pz, bool f32)
{
    const int mat = c >> 5;              // 0..2
    const int k0  = (c & 31) * 32;
    const int b0  = t * 8;

    const void* W = (mat == 0) ? Whh : ((mat == 1) ? U11 : U21);
    const void* X = (mat == 0) ? hb  : ((mat == 1) ? h   : ht);
    const size_t wrow = (size_t)4096 * 1024;

    float acc[8] = {0.f, 0.f, 0.f, 0.f, 0.f, 0.f, 0.f, 0.f};
    if (!f32) {
        const unsigned short* Wp = (const unsigned short*)W;
        const unsigned short* Xp = (const unsigned short*)X;
        #pragma unroll 4
        for (int kk = 0; kk < 32; ++kk) {
            int k = k0 + kk;
            float w = b2f(Wp[wrow + k]);
            ushort4 xa = *reinterpret_cast<const ushort4*>(&Xp[(size_t)k * 2048 + b0]);
            ushort4 xb = *reinterpret_cast<const ushort4*>(&Xp[(size_t)k * 2048 + b0 + 4]);
            acc[0] += w * b2f(xa.x); acc[1] += w * b2f(xa.y);
            acc[2] += w * b2f(xa.z); acc[3] += w * b2f(xa.w);
            acc[4] += w * b2f(xb.x); acc[5] += w * b2f(xb.y);
            acc[6] += w * b2f(xb.z); acc[7] += w * b2f(xb.w);
        }
    } else {
        const float* Wp = (const float*)W;
        const float* Xp = (const float*)X;
        #pragma unroll 4
        for (int kk = 0; kk < 32; ++kk) {
            int k = k0 + kk;
            float w = Wp[wrow + k];
            float4 xa = *reinterpret_cast<const float4*>(&Xp[(size_t)k * 2048 + b0]);
            float4 xb = *reinterpret_cast<const float4*>(&Xp[(size_t)k * 2048 + b0 + 4]);
            acc[0] += w * xa.x; acc[1] += w * xa.y; acc[2] += w * xa.z; acc[3] += w * xa.w;
            acc[4] += w * xb.x; acc[5] += w * xb.y; acc[6] += w * xb.z; acc[7] += w * xb.w;
        }
    }
    #pragma unroll
    for (int j = 0; j < 8; ++j)
        pz[(size_t)c * 2048 + b0 + j] = acc[j];
}

__device__ __forceinline__ void dev_zrow_reduce(
    int b, const float* pz, const void* z_, const void* bias_, void* out_, bool f32)
{
    float a1 = 0.f, a2 = 0.f, a3 = 0.f;
    #pragma unroll
    for (int c = 0; c < 32; ++c)  a1 += pz[(size_t)c * 2048 + b];
    #pragma unroll
    for (int c = 32; c < 64; ++c) a2 += pz[(size_t)c * 2048 + b];
    #pragma unroll
    for (int c = 64; c < 96; ++c) a3 += pz[(size_t)c * 2048 + b];
    float zc = loadf(z_, b, f32);
    float s = a1 + zc * (a2 + a3) + loadf(bias_, 4096, f32);
    float zh = (s + 1.0f) * 0.5f;                 // replicate ref ordering
    zh = fminf(fmaxf(zh, 0.0f), 1.0f);
    float zn = (zh > 0.5f) ? 1.0f : 0.0f;
    if (f32) ((float*)out_)[2 * HB_ELEMS + b] = zn;
    else     ((unsigned short*)out_)[2 * HB_ELEMS + b] = f2b(zn);
}

// ---------------------------------------------------------------------------
// build_bt + zrow_part merged (independent producers; saves one launch)
// ---------------------------------------------------------------------------
__global__ __launch_bounds__(256) void build_plus(
    const void* __restrict__ hb, const void* __restrict__ h,
    const void* __restrict__ ht, const void* __restrict__ z,
    const void* __restrict__ Whh, const void* __restrict__ U11,
    const void* __restrict__ U21,
    unsigned short* __restrict__ BT, float* __restrict__ pz,
    const int* __restrict__ flagp)
{
    const bool f32 = (*flagp != 0);
    if (blockIdx.x < 3072) {
        dev_build_bt(blockIdx.x * 256 + threadIdx.x, hb, h, ht, z, BT, f32);
    } else {
        dev_zrow_part(blockIdx.x - 3072, threadIdx.x, Whh, U11, U21, hb, h, ht, pz, f32);
    }
}

// ---------------------------------------------------------------------------
// Split-K GEMM — round-9 proven config (best measured: ~118 us steady).
// Double-buffered LDS (64 KB), counted-vmcnt pipeline, fenced barriers
// (rule #18), T2 XOR-swizzle (conflicts = 0), waves 2x2, 4x4 fragments,
// XCD-chunked swizzle, grid (16,32,3) = 1536 blocks, 2 blocks/CU.
// ---------------------------------------------------------------------------
__global__ __launch_bounds__(256, 2) void gemm_split(
    const void* __restrict__ Whh, const void* __restrict__ U11, const void* __restrict__ U21,
    const unsigned short* __restrict__ BT,
    unsigned short* __restrict__ P, const int* __restrict__ flagp)
{
    const bool f32 = (*flagp != 0);
    __shared__ __align__(16) unsigned short As[2][128 * 64];
    __shared__ __align__(16) unsigned short Bs[2][128 * 64];

    // ---- XCD swizzle: grid (16,32,3) = 1536 blocks; 192 contiguous ids/XCD
    int id  = (blockIdx.z * 32 + blockIdx.y) * 16 + blockIdx.x;
    int sid = (id & 7) * 192 + (id >> 3);
    const int n0   = (sid & 15) * 128;
    const int j0   = ((sid >> 4) & 31) * 32;
    const int kseg = sid >> 9;            // 0..2
    const void* Asrc = (kseg == 0) ? Whh : ((kseg == 1) ? U11 : U21);
    const int kbase = kseg * 1024;        // BT column base

    const int wave = threadIdx.x >> 6;
    const int lane = threadIdx.x & 63;
    const int srow = wave * 8 + (lane >> 3);               // staging row 0..31
    // T2: pre-swizzled global source chunk; linear LDS dest then holds
    // LDS(row, c) = global chunk c ^ (row&7), with row&7 == lane>>3.
    const int scol_sw = (((lane & 7) ^ (lane >> 3)) * 8);  // element offset
    const int wm = wave >> 1, wn = wave & 1;
    const int lr = lane & 15, kg = lane >> 4;
    const int lr7 = lr & 7;

    f32x4 acc[4][4] = {};

    auto stage = [&](int buf, int k0) {
        #pragma unroll
        for (int r = 0; r < 4; ++r) {
            const unsigned short* g = &BT[(size_t)(n0 + r * 32 + srow) * 3072 + kbase + k0 + scol_sw];
            __builtin_amdgcn_global_load_lds(
                (const __attribute__((address_space(1))) void*)g,
                (__attribute__((address_space(3))) void*)((char*)&Bs[buf][0] + r * 4096 + wave * 1024),
                16, 0, 0);
        }
        if (!f32) {
            #pragma unroll
            for (int r = 0; r < 4; ++r) {
                const unsigned short* g = (const unsigned short*)Asrc
                    + (size_t)(r * 1024 + j0 + srow) * 1024 + k0 + scol_sw;
                __builtin_amdgcn_global_load_lds(
                    (const __attribute__((address_space(1))) void*)g,
                    (__attribute__((address_space(3))) void*)((char*)&As[buf][0] + r * 4096 + wave * 1024),
                    16, 0, 0);
            }
        } else {
            // reg-staged: linear global read, ds_write to swizzled chunk
            #pragma unroll
            for (int r = 0; r < 4; ++r) {
                int trow = r * 32 + srow;
                int dst  = trow * 64 + scol_sw;            // chunk (lane&7)^(row&7)
                const float* g = (const float*)Asrc + (size_t)(r * 1024 + j0 + srow) * 1024
                               + k0 + (lane & 7) * 8;      // linear source chunk
                float4 a0 = *reinterpret_cast<const float4*>(g);
                float4 a1 = *reinterpret_cast<const float4*>(g + 4);
                uint4 v;
                v.x = (unsigned)f2b(a0.x) | ((unsigned)f2b(a0.y) << 16);
                v.y = (unsigned)f2b(a0.z) | ((unsigned)f2b(a0.w) << 16);
                v.z = (unsigned)f2b(a1.x) | ((unsigned)f2b(a1.y) << 16);
                v.w = (unsigned)f2b(a1.z) | ((unsigned)f2b(a1.w) << 16);
                *reinterpret_cast<uint4*>(&As[buf][dst]) = v;
            }
        }
    };

    stage(0, 0);    // prologue: buf0's 8 loads in flight (no drain here)

    #pragma unroll 2
    for (int t = 0; t < 16; ++t) {
        const int cur = t & 1;
        if (t < 15) stage(cur ^ 1, (t + 1) * 64);   // next tile's loads fly over compute

        // Wait for CURRENT tile's loads only (the 8 newest stay outstanding).
        if (f32) {
            asm volatile("s_waitcnt vmcnt(0) lgkmcnt(0)" ::: "memory");
        } else if (t < 15) {
            asm volatile("s_waitcnt vmcnt(8)" ::: "memory");
        } else {
            asm volatile("s_waitcnt vmcnt(0)" ::: "memory");
        }
        __builtin_amdgcn_sched_barrier(0);
        __builtin_amdgcn_s_barrier();               // tile `cur` visible to all waves
        __builtin_amdgcn_sched_barrier(0);

        #pragma unroll
        for (int kk = 0; kk < 64; kk += 32) {
            const int c0 = kk >> 3;                 // global chunk base 0 or 4
            const int csw = ((c0 + kg) ^ lr7) * 8;  // swizzled LDS element offset
            bfx8 av[4], bv[4];
            #pragma unroll
            for (int mi = 0; mi < 4; ++mi)
                av[mi] = *reinterpret_cast<const bfx8*>(
                    &As[cur][(wm * 64 + mi * 16 + lr) * 64 + csw]);
            #pragma unroll
            for (int ni = 0; ni < 4; ++ni)
                bv[ni] = *reinterpret_cast<const bfx8*>(
                    &Bs[cur][(wn * 64 + ni * 16 + lr) * 64 + csw]);
            #pragma unroll
            for (int mi = 0; mi < 4; ++mi)
                #pragma unroll
                for (int ni = 0; ni < 4; ++ni)
                    acc[mi][ni] = __builtin_amdgcn_mfma_f32_16x16x32_bf16(av[mi], bv[ni], acc[mi][ni], 0, 0, 0);
        }

        // Post-compute barrier: pins all ds_reads/MFMAs above it, so next
        // iteration's stage cannot overwrite buf[cur] early.
        __builtin_amdgcn_sched_barrier(0);
        __builtin_amdgcn_s_barrier();
        __builtin_amdgcn_sched_barrier(0);
    }

    // Write bf16 partials. C/D layout: col = lane&15, row = kg*4 + r [m89].
    unsigned short* Pp = P + (size_t)kseg * P_ELEMS;
    #pragma unroll
    for (int mi = 0; mi < 4; ++mi) {
        #pragma unroll
        for (int ni = 0; ni < 4; ++ni) {
            int col = n0 + wn * 64 + ni * 16 + lr;
            #pragma unroll
            for (int r = 0; r < 4; ++r) {
                int trow = wm * 64 + mi * 16 + kg * 4 + r;   // 0..127
                int gate = trow >> 5, jj = trow & 31;
                size_t m = (size_t)gate * 1024 + j0 + jj;
                Pp[m * 2048 + col] = f2b(acc[mi][ni][r]);
            }
        }
    }
}

// ---------------------------------------------------------------------------
// Epilogue (sum 3 bf16 partials + cell math) merged with zrow_reduce.
// ---------------------------------------------------------------------------
__global__ __launch_bounds__(256) void epilogue_plus(
    const unsigned short* __restrict__ P, const float* __restrict__ pz,
    const void* __restrict__ c_, const void* __restrict__ h_,
    const void* __restrict__ z_, const void* __restrict__ zb_,
    const void* __restrict__ bias_, void* __restrict__ out_,
    const int* __restrict__ flagp)
{
    const bool f32 = (*flagp != 0);
    if (blockIdx.x >= 2048) {
        dev_zrow_reduce((blockIdx.x - 2048) * 256 + threadIdx.x, pz, z_, bias_, out_, f32);
        return;
    }
    int tid = blockIdx.x * 256 + threadIdx.x;       // 0 .. 1024*512-1
    int j = tid >> 9;
    int b = (tid & 511) << 2;
    const size_t jb = (size_t)j * 2048 + b;

    float pre[4][4];
    #pragma unroll
    for (int g = 0; g < 4; ++g) {
        size_t row = (size_t)(g * 1024 + j) * 2048 + b;
        ushort4 s0 = *reinterpret_cast<const ushort4*>(&P[row]);
        ushort4 s1 = *reinterpret_cast<const ushort4*>(&P[P_ELEMS + row]);
        ushort4 s2 = *reinterpret_cast<const ushort4*>(&P[2 * P_ELEMS + row]);
        float bv = loadf(bias_, g * 1024 + j, f32);
        pre[g][0] = b2f(s0.x) + b2f(s1.x) + b2f(s2.x) + bv;
        pre[g][1] = b2f(s0.y) + b2f(s1.y) + b2f(s2.y) + bv;
        pre[g][2] = b2f(s0.z) + b2f(s1.z) + b2f(s2.z) + bv;
        pre[g][3] = b2f(s0.w) + b2f(s1.w) + b2f(s2.w) + bv;
    }

    float hn[4], cn[4];
    #pragma unroll
    for (int e = 0; e < 4; ++e) {
        float zc = loadf(z_, b + e, f32);
        float zv = loadf(zb_, b + e, f32);
        float cc = loadf(c_, jb + e, f32);
        float hh = loadf(h_, jb + e, f32);
        cell_math(pre[0][e], pre[1][e], pre[2][e], pre[3][e], cc, hh, zc, zv, hn[e], cn[e]);
    }
    if (f32) {
        float4 ho = {hn[0], hn[1], hn[2], hn[3]};
        float4 co = {cn[0], cn[1], cn[2], cn[3]};
        *reinterpret_cast<float4*>(&((float*)out_)[jb]) = ho;
        *reinterpret_cast<float4*>(&((float*)out_)[HB_ELEMS + jb]) = co;
    } else {
        ushort4 ho = {f2b(hn[0]), f2b(hn[1]), f2b(hn[2]), f2b(hn[3])};
        ushort4 co = {f2b(cn[0]), f2b(cn[1]), f2b(cn[2]), f2b(cn[3])};
        *reinterpret_cast<ushort4*>(&((unsigned short*)out_)[jb]) = ho;
        *reinterpret_cast<ushort4*>(&((unsigned short*)out_)[HB_ELEMS + jb]) = co;
    }
}

// ---------------------------------------------------------------------------
// Fallback path kernels (small ws) — standalone versions
// ---------------------------------------------------------------------------
__global__ __launch_bounds__(256) void build_bt_k(
    const void* __restrict__ hb, const void* __restrict__ h,
    const void* __restrict__ ht, const void* __restrict__ z,
    unsigned short* __restrict__ BT, const int* __restrict__ flagp)
{
    dev_build_bt(blockIdx.x * 256 + threadIdx.x, hb, h, ht, z, BT, (*flagp != 0));
}

__global__ __launch_bounds__(256) void gemm_fused(
    const void* __restrict__ Whh, const void* __restrict__ U11, const void* __restrict__ U21,
    const unsigned short* __restrict__ BT,
    const void* __restrict__ c_, const void* __restrict__ h_,
    const void* __restrict__ z_, const void* __restrict__ zb_,
    const void* __restrict__ bias_, void* __restrict__ out_,
    const int* __restrict__ flagp)
{
    const bool f32 = (*flagp != 0);
    __shared__ __align__(16) unsigned short As[128 * 64];
    __shared__ __align__(16) unsigned short Bs[128 * 64];

    const int n0 = blockIdx.x * 128;
    const int j0 = blockIdx.y * 32;
    const int wave = threadIdx.x >> 6;
    const int lane = threadIdx.x & 63;
    const int srow = wave * 8 + (lane >> 3);
    const int scol = (lane & 7) * 8;
    const int lr = lane & 15, kg = lane >> 4;

    f32x4 acc[8][2] = {};

    for (int k0 = 0; k0 < 3072; k0 += 64) {
        int seg = k0 >> 10, kl = k0 & 1023;
        const void* Asrc = (seg == 0) ? Whh : ((seg == 1) ? U11 : U21);

        __syncthreads();
        #pragma unroll
        for (int r = 0; r < 4; ++r) {
            const unsigned short* g = &BT[(size_t)(n0 + r * 32 + srow) * 3072 + k0 + scol];
            __builtin_amdgcn_global_load_lds(
                (const __attribute__((address_space(1))) void*)g,
                (__attribute__((address_space(3))) void*)((char*)Bs + r * 4096 + wave * 1024),
                16, 0, 0);
        }
        if (!f32) {
            #pragma unroll
            for (int r = 0; r < 4; ++r) {
                const unsigned short* g = (const unsigned short*)Asrc
                    + (size_t)(r * 1024 + j0 + srow) * 1024 + kl + scol;
                __builtin_amdgcn_global_load_lds(
                    (const __attribute__((address_space(1))) void*)g,
                    (__attribute__((address_space(3))) void*)((char*)As + r * 4096 + wave * 1024),
                    16, 0, 0);
            }
        } else {
            #pragma unroll
            for (int r = 0; r < 4; ++r) {
                int trow = r * 32 + srow;
                const float* g = (const float*)Asrc + (size_t)(r * 1024 + j0 + srow) * 1024 + kl + scol;
                float4 a0 = *reinterpret_cast<const float4*>(g);
                float4 a1 = *reinterpret_cast<const float4*>(g + 4);
                uint4 v;
                v.x = (unsigned)f2b(a0.x) | ((unsigned)f2b(a0.y) << 16);
                v.y = (unsigned)f2b(a0.z) | ((unsigned)f2b(a0.w) << 16);
                v.z = (unsigned)f2b(a1.x) | ((unsigned)f2b(a1.y) << 16);
                v.w = (unsigned)f2b(a1.z) | ((unsigned)f2b(a1.w) << 16);
                *reinterpret_cast<uint4*>(&As[trow * 64 + scol]) = v;
            }
        }
        __syncthreads();

        #pragma unroll
        for (int kk = 0; kk < 64; kk += 32) {
            bfx8 bv0 = *reinterpret_cast<const bfx8*>(&Bs[(wave * 32 + lr) * 64 + kk + kg * 8]);
            bfx8 bv1 = *reinterpret_cast<const bfx8*>(&Bs[(wave * 32 + 16 + lr) * 64 + kk + kg * 8]);
            #pragma unroll
            for (int mi = 0; mi < 8; ++mi) {
                bfx8 af = *reinterpret_cast<const bfx8*>(&As[(mi * 16 + lr) * 64 + kk + kg * 8]);
                acc[mi][0] = __builtin_amdgcn_mfma_f32_16x16x32_bf16(af, bv0, acc[mi][0], 0, 0, 0);
                acc[mi][1] = __builtin_amdgcn_mfma_f32_16x16x32_bf16(af, bv1, acc[mi][1], 0, 0, 0);
            }
        }
    }

    #pragma unroll
    for (int ni = 0; ni < 2; ++ni) {
        int b = n0 + wave * 32 + ni * 16 + lr;
        float zc = loadf(z_, b, f32);
        float zv = loadf(zb_, b, f32);
        #pragma unroll
        for (int mh = 0; mh < 2; ++mh) {
            #pragma unroll
            for (int r = 0; r < 4; ++r) {
                int j = j0 + mh * 16 + kg * 4 + r;
                float fp = acc[0 + mh][ni][r] + loadf(bias_, j, f32);
                float ip = acc[2 + mh][ni][r] + loadf(bias_, 1024 + j, f32);
                float op = acc[4 + mh][ni][r] + loadf(bias_, 2048 + j, f32);
                float gp = acc[6 + mh][ni][r] + loadf(bias_, 3072 + j, f32);
                float cc = loadf(c_, (size_t)j * 2048 + b, f32);
                float hh = loadf(h_, (size_t)j * 2048 + b, f32);
                float hn, cn;
                cell_math(fp, ip, op, gp, cc, hh, zc, zv, hn, cn);
                if (f32) {
                    ((float*)out_)[(size_t)j * 2048 + b] = hn;
                    ((float*)out_)[HB_ELEMS + (size_t)j * 2048 + b] = cn;
                } else {
                    ((unsigned short*)out_)[(size_t)j * 2048 + b] = f2b(hn);
                    ((unsigned short*)out_)[HB_ELEMS + (size_t)j * 2048 + b] = f2b(cn);
                }
            }
        }
    }
}

__global__ __launch_bounds__(256) void zrow_k(
    const void* __restrict__ Whh, const void* __restrict__ U11, const void* __restrict__ U21,
    const void* __restrict__ hb, const void* __restrict__ h, const void* __restrict__ ht,
    const void* __restrict__ z_, const void* __restrict__ bias_,
    void* __restrict__ out_, const int* __restrict__ flagp)
{
    const bool f32 = (*flagp != 0);
    int b = blockIdx.x * 256 + threadIdx.x;
    float a1 = 0.f, a2 = 0.f, a3 = 0.f;
    const size_t wrow = (size_t)4096 * 1024;
    for (int k = 0; k < 1024; ++k) {
        a1 += loadf(Whh, wrow + k, f32) * loadf(hb, (size_t)k * 2048 + b, f32);
        a2 += loadf(U11, wrow + k, f32) * loadf(h,  (size_t)k * 2048 + b, f32);
        a3 += loadf(U21, wrow + k, f32) * loadf(ht, (size_t)k * 2048 + b, f32);
    }
    float zc = loadf(z_, b, f32);
    float s = a1 + zc * (a2 + a3) + loadf(bias_, 4096, f32);
    float zh = (s + 1.0f) * 0.5f;
    zh = fminf(fmaxf(zh, 0.0f), 1.0f);
    float zn = (zh > 0.5f) ? 1.0f : 0.0f;
    if (f32) ((float*)out_)[2 * HB_ELEMS + b] = zn;
    else     ((unsigned short*)out_)[2 * HB_ELEMS + b] = f2b(zn);
}

__global__ __launch_bounds__(256) void fallback_k(
    const void* __restrict__ Whh, const void* __restrict__ U11, const void* __restrict__ U21,
    const void* __restrict__ hb, const void* __restrict__ h, const void* __restrict__ ht,
    const void* __restrict__ c_, const void* __restrict__ z_, const void* __restrict__ zb_,
    const void* __restrict__ bias_, void* __restrict__ out_, const int* __restrict__ flagp)
{
    const bool f32 = (*flagp != 0);
    int b = blockIdx.x * 256 + threadIdx.x;
    int j = blockIdx.y;
    float zc = loadf(z_, b, f32);
    float a[4] = {0.f, 0.f, 0.f, 0.f};
    for (int k = 0; k < 1024; ++k) {
        float xb = loadf(hb, (size_t)k * 2048 + b, f32);
        #pragma unroll
        for (int g = 0; g < 4; ++g)
            a[g] += loadf(Whh, (size_t)(g * 1024 + j) * 1024 + k, f32) * xb;
    }
    for (int k = 0; k < 1024; ++k) {
        float xh = zc * loadf(h, (size_t)k * 2048 + b, f32);
        #pragma unroll
        for (int g = 0; g < 4; ++g)
            a[g] += loadf(U11, (size_t)(g * 1024 + j) * 1024 + k, f32) * xh;
    }
    for (int k = 0; k < 1024; ++k) {
        float xt = zc * loadf(ht, (size_t)k * 2048 + b, f32);
        #pragma unroll
        for (int g = 0; g < 4; ++g)
            a[g] += loadf(U21, (size_t)(g * 1024 + j) * 1024 + k, f32) * xt;
    }
    float fp = a[0] + loadf(bias_, j, f32);
    float ip = a[1] + loadf(bias_, 1024 + j, f32);
    float op = a[2] + loadf(bias_, 2048 + j, f32);
    float gp = a[3] + loadf(bias_, 3072 + j, f32);
    float cc = loadf(c_, (size_t)j * 2048 + b, f32);
    float hh = loadf(h,  (size_t)j * 2048 + b, f32);
    float zv = loadf(zb_, b, f32);
    float hn, cn;
    cell_math(fp, ip, op, gp, cc, hh, zc, zv, hn, cn);
    if (f32) {
        ((float*)out_)[(size_t)j * 2048 + b] = hn;
        ((float*)out_)[HB_ELEMS + (size_t)j * 2048 + b] = cn;
    } else {
        ((unsigned short*)out_)[(size_t)j * 2048 + b] = f2b(hn);
        ((unsigned short*)out_)[HB_ELEMS + (size_t)j * 2048 + b] = f2b(cn);
    }
}

// ---------------------------------------------------------------------------
extern "C" void kernel_launch(void* const* d_in, const int* in_sizes, int n_in,
                              void* d_out, int out_size, void* d_ws, size_t ws_size,
                              hipStream_t stream)
{
    // setup_inputs order: c, h_bottom, h, h_top, z, z_bottom, W_hh, U_11, U_21, bias
    const void* c    = d_in[0];
    const void* hb   = d_in[1];
    const void* h    = d_in[2];
    const void* ht   = d_in[3];
    const void* z    = d_in[4];
    const void* zb   = d_in[5];
    const void* Whh  = d_in[6];
    const void* U11  = d_in[7];
    const void* U21  = d_in[8];
    const void* bias = d_in[9];

    int* flag = (int*)d_ws;
    unsigned short* BT = (unsigned short*)((char*)d_ws + 4096);
    const size_t bt_bytes = (size_t)2048 * 3072 * 2;                 // 12.58 MB
    float* pz = (float*)((char*)d_ws + 4096 + bt_bytes);
    const size_t pz_bytes = (size_t)96 * 2048 * 4;                   // 768 KB
    unsigned short* P = (unsigned short*)((char*)d_ws + 4096 + bt_bytes + pz_bytes);
    const size_t p_bytes = 3 * P_ELEMS * 2;                          // 50.3 MB (bf16)

    const size_t need_bt    = 4096 + bt_bytes;
    const size_t need_pz    = need_bt + pz_bytes;
    const size_t need_split = need_pz + p_bytes;                     // ~63.7 MB

    if (ws_size < 4) return;

    detect_k<<<1, 64, 0, stream>>>((const unsigned short*)Whh, flag);

    if (ws_size >= need_split) {
        // main path: 4 launches total
        build_plus<<<3072 + 96, 256, 0, stream>>>(hb, h, ht, z, Whh, U11, U21, BT, pz, flag);
        gemm_split<<<dim3(16, 32, 3), 256, 0, stream>>>(Whh, U11, U21, BT, P, flag);
        epilogue_plus<<<2048 + 8, 256, 0, stream>>>(P, pz, c, h, z, zb, bias, d_out, flag);
    } else if (ws_size >= need_bt) {
        build_bt_k<<<3072, 256, 0, stream>>>(hb, h, ht, z, BT, flag);
        gemm_fused<<<dim3(16, 32), 256, 0, stream>>>(Whh, U11, U21, BT,
                                                     c, h, z, zb, bias, d_out, flag);
        zrow_k<<<8, 256, 0, stream>>>(Whh, U11, U21, hb, h, ht, z, bias, d_out, flag);
    } else {
        fallback_k<<<dim3(8, 1024), 256, 0, stream>>>(Whh, U11, U21, hb, h, ht,
                                                      c, z, zb, bias, d_out, flag);
        zrow_k<<<8, 256, 0, stream>>>(Whh, U11, U21, hb, h, ht, z, bias, d_out, flag);
    }
}

// Round 14
// 128.869 us; speedup vs baseline: 1.2419x; 1.0393x over previous
//
#include <hip/hip_runtime.h>
#include <hip/hip_bf16.h>

#define HB_ELEMS ((size_t)1024 * 2048)   // elements in one H x B output
#define P_ELEMS  ((size_t)4096 * 2048)   // one split-K partial

typedef __bf16 bfx8 __attribute__((ext_vector_type(8)));
typedef float f32x4 __attribute__((ext_vector_type(4)));

__device__ __forceinline__ float b2f(unsigned short u) {
    union { unsigned int i; float f; } v; v.i = ((unsigned int)u) << 16; return v.f;
}
__device__ __forceinline__ unsigned short f2b(float f) {
    __hip_bfloat16 h = __float2bfloat16(f);
    return *reinterpret_cast<unsigned short*>(&h);
}
__device__ __forceinline__ float loadf(const void* p, size_t i, bool f32) {
    return f32 ? ((const float*)p)[i] : b2f(((const unsigned short*)p)[i]);
}
__device__ __forceinline__ float sigf(float x) { return 1.0f / (1.0f + __expf(-x)); }

__device__ __forceinline__ void cell_math(float fp, float ip, float op, float gp,
                                           float cc, float hh, float zc, float zv,
                                           float& hn, float& cn) {
    float f = sigf(fp), i = sigf(ip), o = sigf(op), g = tanhf(gp);
    float ig = i * g;
    cn = zc * ig + (1.0f - zc) * (1.0f - zv) * cc + (1.0f - zc) * zv * (f * cc + ig);
    float tc = tanhf(cn);
    hn = zc * o * tc + (1.0f - zc) * (1.0f - zv) * hh + (1.0f - zc) * zv * o * tc;
}

// ---------------------------------------------------------------------------
// dtype detector (1 wave)
// ---------------------------------------------------------------------------
__global__ void detect_k(const unsigned short* __restrict__ w, int* __restrict__ flag) {
    int lane = threadIdx.x;
    bool hit = false;
    #pragma unroll
    for (int i = 0; i < 4; ++i) {
        unsigned e = (w[lane + i * 64] >> 7) & 0xFF;
        hit |= (e >= 126);
    }
    unsigned long long m = __ballot(hit);
    if (lane == 0) *flag = (m != 0ULL) ? 1 : 0;
}

// ---------------------------------------------------------------------------
// device bodies (shared by merged + standalone kernels)
// ---------------------------------------------------------------------------
__device__ __forceinline__ void dev_build_bt(
    int tid, const void* hb, const void* h, const void* ht, const void* z,
    unsigned short* BT, bool f32)
{
    int b   = tid & 2047;
    int kg8 = tid >> 11;            // 0..383
    int k   = kg8 * 8;

    const void* src; int kl; bool sc;
    if (k < 1024)      { src = hb; kl = k;        sc = false; }
    else if (k < 2048) { src = h;  kl = k - 1024; sc = true;  }
    else               { src = ht; kl = k - 2048; sc = true;  }

    bool zero = sc && (loadf(z, b, f32) == 0.0f);   // z is exactly 0.0 or 1.0
    unsigned short t[8];
    if (zero) {
        #pragma unroll
        for (int j = 0; j < 8; ++j) t[j] = 0;
    } else if (f32) {
        #pragma unroll
        for (int j = 0; j < 8; ++j) t[j] = f2b(((const float*)src)[(size_t)(kl + j) * 2048 + b]);
    } else {
        #pragma unroll
        for (int j = 0; j < 8; ++j) t[j] = ((const unsigned short*)src)[(size_t)(kl + j) * 2048 + b];
    }
    uint4 v;
    v.x = (unsigned)t[0] | ((unsigned)t[1] << 16);
    v.y = (unsigned)t[2] | ((unsigned)t[3] << 16);
    v.z = (unsigned)t[4] | ((unsigned)t[5] << 16);
    v.w = (unsigned)t[6] | ((unsigned)t[7] << 16);
    *reinterpret_cast<uint4*>(&BT[(size_t)b * 3072 + k]) = v;
}

__device__ __forceinline__ void dev_zrow_part(
    int c, int t, const void* Whh, const void* U11, const void* U21,
    const void* hb, const void* h, const void* ht, float* pz, bool f32)
{
    const int mat = c >> 5;              // 0..2
    const int k0  = (c & 31) * 32;
    const int b0  = t * 8;

    const void* W = (mat == 0) ? Whh : ((mat == 1) ? U11 : U21);
    const void* X = (mat == 0) ? hb  : ((mat == 1) ? h   : ht);
    const size_t wrow = (size_t)4096 * 1024;

    float acc[8] = {0.f, 0.f, 0.f, 0.f, 0.f, 0.f, 0.f, 0.f};
    if (!f32) {
        const unsigned short* Wp = (const unsigned short*)W;
        const unsigned short* Xp = (const unsigned short*)X;
        #pragma unroll 4
        for (int kk = 0; kk < 32; ++kk) {
            int k = k0 + kk;
            float w = b2f(Wp[wrow + k]);
            ushort4 xa = *reinterpret_cast<const ushort4*>(&Xp[(size_t)k * 2048 + b0]);
            ushort4 xb = *reinterpret_cast<const ushort4*>(&Xp[(size_t)k * 2048 + b0 + 4]);
            acc[0] += w * b2f(xa.x); acc[1] += w * b2f(xa.y);
            acc[2] += w * b2f(xa.z); acc[3] += w * b2f(xa.w);
            acc[4] += w * b2f(xb.x); acc[5] += w * b2f(xb.y);
            acc[6] += w * b2f(xb.z); acc[7] += w * b2f(xb.w);
        }
    } else {
        const float* Wp = (const float*)W;
        const float* Xp = (const float*)X;
        #pragma unroll 4
        for (int kk = 0; kk < 32; ++kk) {
            int k = k0 + kk;
            float w = Wp[wrow + k];
            float4 xa = *reinterpret_cast<const float4*>(&Xp[(size_t)k * 2048 + b0]);
            float4 xb = *reinterpret_cast<const float4*>(&Xp[(size_t)k * 2048 + b0 + 4]);
            acc[0] += w * xa.x; acc[1] += w * xa.y; acc[2] += w * xa.z; acc[3] += w * xa.w;
            acc[4] += w * xb.x; acc[5] += w * xb.y; acc[6] += w * xb.z; acc[7] += w * xb.w;
        }
    }
    #pragma unroll
    for (int j = 0; j < 8; ++j)
        pz[(size_t)c * 2048 + b0 + j] = acc[j];
}

__device__ __forceinline__ void dev_zrow_reduce(
    int b, const float* pz, const void* z_, const void* bias_, void* out_, bool f32)
{
    float a1 = 0.f, a2 = 0.f, a3 = 0.f;
    #pragma unroll
    for (int c = 0; c < 32; ++c)  a1 += pz[(size_t)c * 2048 + b];
    #pragma unroll
    for (int c = 32; c < 64; ++c) a2 += pz[(size_t)c * 2048 + b];
    #pragma unroll
    for (int c = 64; c < 96; ++c) a3 += pz[(size_t)c * 2048 + b];
    float zc = loadf(z_, b, f32);
    float s = a1 + zc * (a2 + a3) + loadf(bias_, 4096, f32);
    float zh = (s + 1.0f) * 0.5f;                 // replicate ref ordering
    zh = fminf(fmaxf(zh, 0.0f), 1.0f);
    float zn = (zh > 0.5f) ? 1.0f : 0.0f;
    if (f32) ((float*)out_)[2 * HB_ELEMS + b] = zn;
    else     ((unsigned short*)out_)[2 * HB_ELEMS + b] = f2b(zn);
}

// ---------------------------------------------------------------------------
// build_bt + zrow_part merged (independent producers; saves one launch)
// ---------------------------------------------------------------------------
__global__ __launch_bounds__(256) void build_plus(
    const void* __restrict__ hb, const void* __restrict__ h,
    const void* __restrict__ ht, const void* __restrict__ z,
    const void* __restrict__ Whh, const void* __restrict__ U11,
    const void* __restrict__ U21,
    unsigned short* __restrict__ BT, float* __restrict__ pz,
    const int* __restrict__ flagp)
{
    const bool f32 = (*flagp != 0);
    if (blockIdx.x < 3072) {
        dev_build_bt(blockIdx.x * 256 + threadIdx.x, hb, h, ht, z, BT, f32);
    } else {
        dev_zrow_part(blockIdx.x - 3072, threadIdx.x, Whh, U11, U21, hb, h, ht, pz, f32);
    }
}

// ---------------------------------------------------------------------------
// Split-K GEMM, BK=32: 32 KB dbuf LDS -> 4 blocks/CU (16 waves, 50% cap);
// counted-vmcnt pipeline (steady vmcnt(4)) + fenced barriers (rule #18).
// T2 swizzle for 4-chunk rows: LDS(row,q) = global chunk q ^ ((row>>1)&3)
// (even-row 16-lane groups cover each bank-half exactly 2x -> 2-way = free).
// Waves 2x2, 4x4 fragments, 16 MFMA + 8 ds_read_b128 per wave per K-step,
// 32 K-steps. XCD-chunked swizzle, grid (16,32,3) = 1536 blocks.
// ---------------------------------------------------------------------------
__global__ __launch_bounds__(256, 4) void gemm_split(
    const void* __restrict__ Whh, const void* __restrict__ U11, const void* __restrict__ U21,
    const unsigned short* __restrict__ BT,
    unsigned short* __restrict__ P, const int* __restrict__ flagp)
{
    const bool f32 = (*flagp != 0);
    __shared__ __align__(16) unsigned short As[2][128 * 32];   // 8 KB each
    __shared__ __align__(16) unsigned short Bs[2][128 * 32];

    // ---- XCD swizzle: grid (16,32,3) = 1536 blocks; 192 contiguous ids/XCD
    int id  = (blockIdx.z * 32 + blockIdx.y) * 16 + blockIdx.x;
    int sid = (id & 7) * 192 + (id >> 3);
    const int n0   = (sid & 15) * 128;
    const int j0   = ((sid >> 4) & 31) * 32;
    const int kseg = sid >> 9;            // 0..2
    const void* Asrc = (kseg == 0) ? Whh : ((kseg == 1) ? U11 : U21);
    const int kbase = kseg * 1024;        // BT column base

    const int wave = threadIdx.x >> 6;
    const int lane = threadIdx.x & 63;
    // staging map: per round, thread covers (row = wave*16 + lane>>2 [+64*rnd], chunk q = lane&3)
    const int srow0 = wave * 16 + (lane >> 2);   // 0..63
    const int sq    = lane & 3;
    const int wm = wave >> 1, wn = wave & 1;
    const int lr = lane & 15, kg = lane >> 4;

    f32x4 acc[4][4] = {};

    auto stage = [&](int buf, int k0) {
        #pragma unroll
        for (int rnd = 0; rnd < 2; ++rnd) {
            const int row  = srow0 + rnd * 64;                 // 0..127
            const int gcol = (sq ^ ((row >> 1) & 3)) * 8;      // pre-swizzled global chunk
            // B
            const unsigned short* gB = &BT[(size_t)(n0 + row) * 3072 + kbase + k0 + gcol];
            __builtin_amdgcn_global_load_lds(
                (const __attribute__((address_space(1))) void*)gB,
                (__attribute__((address_space(3))) void*)((char*)&Bs[buf][0] + rnd * 4096 + wave * 1024),
                16, 0, 0);
            // A
            const size_t arow = (size_t)((row >> 5) * 1024 + j0 + (row & 31));
            if (!f32) {
                const unsigned short* gA = (const unsigned short*)Asrc + arow * 1024 + k0 + gcol;
                __builtin_amdgcn_global_load_lds(
                    (const __attribute__((address_space(1))) void*)gA,
                    (__attribute__((address_space(3))) void*)((char*)&As[buf][0] + rnd * 4096 + wave * 1024),
                    16, 0, 0);
            } else {
                const float* gA = (const float*)Asrc + arow * 1024 + k0 + gcol;
                float4 a0 = *reinterpret_cast<const float4*>(gA);
                float4 a1 = *reinterpret_cast<const float4*>(gA + 4);
                uint4 v;
                v.x = (unsigned)f2b(a0.x) | ((unsigned)f2b(a0.y) << 16);
                v.y = (unsigned)f2b(a0.z) | ((unsigned)f2b(a0.w) << 16);
                v.z = (unsigned)f2b(a1.x) | ((unsigned)f2b(a1.y) << 16);
                v.w = (unsigned)f2b(a1.z) | ((unsigned)f2b(a1.w) << 16);
                // dest = linear slot (row, sq) — same place gload_lds would write
                *reinterpret_cast<uint4*>(&As[buf][row * 32 + sq * 8]) = v;
            }
        }
    };

    stage(0, 0);    // prologue: tile 0's 4 loads in flight

    #pragma unroll 2
    for (int t = 0; t < 32; ++t) {
        const int cur = t & 1;
        if (t < 31) stage(cur ^ 1, (t + 1) * 32);   // next tile's loads fly over compute

        // Wait for CURRENT tile's loads only (4 newest stay outstanding).
        if (f32) {
            asm volatile("s_waitcnt vmcnt(0) lgkmcnt(0)" ::: "memory");
        } else if (t < 31) {
            asm volatile("s_waitcnt vmcnt(4)" ::: "memory");
        } else {
            asm volatile("s_waitcnt vmcnt(0)" ::: "memory");
        }
        __builtin_amdgcn_sched_barrier(0);
        __builtin_amdgcn_s_barrier();               // tile `cur` visible to all waves
        __builtin_amdgcn_sched_barrier(0);

        bfx8 av[4], bv[4];
        #pragma unroll
        for (int mi = 0; mi < 4; ++mi) {
            int r = wm * 64 + mi * 16 + lr;
            av[mi] = *reinterpret_cast<const bfx8*>(
                &As[cur][r * 32 + ((kg ^ ((r >> 1) & 3)) * 8)]);
        }
        #pragma unroll
        for (int ni = 0; ni < 4; ++ni) {
            int r = wn * 64 + ni * 16 + lr;
            bv[ni] = *reinterpret_cast<const bfx8*>(
                &Bs[cur][r * 32 + ((kg ^ ((r >> 1) & 3)) * 8)]);
        }
        #pragma unroll
        for (int mi = 0; mi < 4; ++mi)
            #pragma unroll
            for (int ni = 0; ni < 4; ++ni)
                acc[mi][ni] = __builtin_amdgcn_mfma_f32_16x16x32_bf16(av[mi], bv[ni], acc[mi][ni], 0, 0, 0);

        // Post-compute barrier: pins all ds_reads/MFMAs above it, so next
        // iteration's stage cannot overwrite buf[cur] early.
        __builtin_amdgcn_sched_barrier(0);
        __builtin_amdgcn_s_barrier();
        __builtin_amdgcn_sched_barrier(0);
    }

    // Write bf16 partials. C/D layout: col = lane&15, row = kg*4 + r [m89].
    unsigned short* Pp = P + (size_t)kseg * P_ELEMS;
    #pragma unroll
    for (int mi = 0; mi < 4; ++mi) {
        #pragma unroll
        for (int ni = 0; ni < 4; ++ni) {
            int col = n0 + wn * 64 + ni * 16 + lr;
            #pragma unroll
            for (int r = 0; r < 4; ++r) {
                int trow = wm * 64 + mi * 16 + kg * 4 + r;   // 0..127
                int gate = trow >> 5, jj = trow & 31;
                size_t m = (size_t)gate * 1024 + j0 + jj;
                Pp[m * 2048 + col] = f2b(acc[mi][ni][r]);
            }
        }
    }
}

// ---------------------------------------------------------------------------
// Epilogue (sum 3 bf16 partials + cell math) merged with zrow_reduce.
// ---------------------------------------------------------------------------
__global__ __launch_bounds__(256) void epilogue_plus(
    const unsigned short* __restrict__ P, const float* __restrict__ pz,
    const void* __restrict__ c_, const void* __restrict__ h_,
    const void* __restrict__ z_, const void* __restrict__ zb_,
    const void* __restrict__ bias_, void* __restrict__ out_,
    const int* __restrict__ flagp)
{
    const bool f32 = (*flagp != 0);
    if (blockIdx.x >= 2048) {
        dev_zrow_reduce((blockIdx.x - 2048) * 256 + threadIdx.x, pz, z_, bias_, out_, f32);
        return;
    }
    int tid = blockIdx.x * 256 + threadIdx.x;       // 0 .. 1024*512-1
    int j = tid >> 9;
    int b = (tid & 511) << 2;
    const size_t jb = (size_t)j * 2048 + b;

    float pre[4][4];
    #pragma unroll
    for (int g = 0; g < 4; ++g) {
        size_t row = (size_t)(g * 1024 + j) * 2048 + b;
        ushort4 s0 = *reinterpret_cast<const ushort4*>(&P[row]);
        ushort4 s1 = *reinterpret_cast<const ushort4*>(&P[P_ELEMS + row]);
        ushort4 s2 = *reinterpret_cast<const ushort4*>(&P[2 * P_ELEMS + row]);
        float bv = loadf(bias_, g * 1024 + j, f32);
        pre[g][0] = b2f(s0.x) + b2f(s1.x) + b2f(s2.x) + bv;
        pre[g][1] = b2f(s0.y) + b2f(s1.y) + b2f(s2.y) + bv;
        pre[g][2] = b2f(s0.z) + b2f(s1.z) + b2f(s2.z) + bv;
        pre[g][3] = b2f(s0.w) + b2f(s1.w) + b2f(s2.w) + bv;
    }

    float hn[4], cn[4];
    #pragma unroll
    for (int e = 0; e < 4; ++e) {
        float zc = loadf(z_, b + e, f32);
        float zv = loadf(zb_, b + e, f32);
        float cc = loadf(c_, jb + e, f32);
        float hh = loadf(h_, jb + e, f32);
        cell_math(pre[0][e], pre[1][e], pre[2][e], pre[3][e], cc, hh, zc, zv, hn[e], cn[e]);
    }
    if (f32) {
        float4 ho = {hn[0], hn[1], hn[2], hn[3]};
        float4 co = {cn[0], cn[1], cn[2], cn[3]};
        *reinterpret_cast<float4*>(&((float*)out_)[jb]) = ho;
        *reinterpret_cast<float4*>(&((float*)out_)[HB_ELEMS + jb]) = co;
    } else {
        ushort4 ho = {f2b(hn[0]), f2b(hn[1]), f2b(hn[2]), f2b(hn[3])};
        ushort4 co = {f2b(cn[0]), f2b(cn[1]), f2b(cn[2]), f2b(cn[3])};
        *reinterpret_cast<ushort4*>(&((unsigned short*)out_)[jb]) = ho;
        *reinterpret_cast<ushort4*>(&((unsigned short*)out_)[HB_ELEMS + jb]) = co;
    }
}

// ---------------------------------------------------------------------------
// Fallback path kernels (small ws) — standalone versions
// ---------------------------------------------------------------------------
__global__ __launch_bounds__(256) void build_bt_k(
    const void* __restrict__ hb, const void* __restrict__ h,
    const void* __restrict__ ht, const void* __restrict__ z,
    unsigned short* __restrict__ BT, const int* __restrict__ flagp)
{
    dev_build_bt(blockIdx.x * 256 + threadIdx.x, hb, h, ht, z, BT, (*flagp != 0));
}

__global__ __launch_bounds__(256) void gemm_fused(
    const void* __restrict__ Whh, const void* __restrict__ U11, const void* __restrict__ U21,
    const unsigned short* __restrict__ BT,
    const void* __restrict__ c_, const void* __restrict__ h_,
    const void* __restrict__ z_, const void* __restrict__ zb_,
    const void* __restrict__ bias_, void* __restrict__ out_,
    const int* __restrict__ flagp)
{
    const bool f32 = (*flagp != 0);
    __shared__ __align__(16) unsigned short As[128 * 64];
    __shared__ __align__(16) unsigned short Bs[128 * 64];

    const int n0 = blockIdx.x * 128;
    const int j0 = blockIdx.y * 32;
    const int wave = threadIdx.x >> 6;
    const int lane = threadIdx.x & 63;
    const int srow = wave * 8 + (lane >> 3);
    const int scol = (lane & 7) * 8;
    const int lr = lane & 15, kg = lane >> 4;

    f32x4 acc[8][2] = {};

    for (int k0 = 0; k0 < 3072; k0 += 64) {
        int seg = k0 >> 10, kl = k0 & 1023;
        const void* Asrc = (seg == 0) ? Whh : ((seg == 1) ? U11 : U21);

        __syncthreads();
        #pragma unroll
        for (int r = 0; r < 4; ++r) {
            const unsigned short* g = &BT[(size_t)(n0 + r * 32 + srow) * 3072 + k0 + scol];
            __builtin_amdgcn_global_load_lds(
                (const __attribute__((address_space(1))) void*)g,
                (__attribute__((address_space(3))) void*)((char*)Bs + r * 4096 + wave * 1024),
                16, 0, 0);
        }
        if (!f32) {
            #pragma unroll
            for (int r = 0; r < 4; ++r) {
                const unsigned short* g = (const unsigned short*)Asrc
                    + (size_t)(r * 1024 + j0 + srow) * 1024 + kl + scol;
                __builtin_amdgcn_global_load_lds(
                    (const __attribute__((address_space(1))) void*)g,
                    (__attribute__((address_space(3))) void*)((char*)As + r * 4096 + wave * 1024),
                    16, 0, 0);
            }
        } else {
            #pragma unroll
            for (int r = 0; r < 4; ++r) {
                int trow = r * 32 + srow;
                const float* g = (const float*)Asrc + (size_t)(r * 1024 + j0 + srow) * 1024 + kl + scol;
                float4 a0 = *reinterpret_cast<const float4*>(g);
                float4 a1 = *reinterpret_cast<const float4*>(g + 4);
                uint4 v;
                v.x = (unsigned)f2b(a0.x) | ((unsigned)f2b(a0.y) << 16);
                v.y = (unsigned)f2b(a0.z) | ((unsigned)f2b(a0.w) << 16);
                v.z = (unsigned)f2b(a1.x) | ((unsigned)f2b(a1.y) << 16);
                v.w = (unsigned)f2b(a1.z) | ((unsigned)f2b(a1.w) << 16);
                *reinterpret_cast<uint4*>(&As[trow * 64 + scol]) = v;
            }
        }
        __syncthreads();

        #pragma unroll
        for (int kk = 0; kk < 64; kk += 32) {
            bfx8 bv0 = *reinterpret_cast<const bfx8*>(&Bs[(wave * 32 + lr) * 64 + kk + kg * 8]);
            bfx8 bv1 = *reinterpret_cast<const bfx8*>(&Bs[(wave * 32 + 16 + lr) * 64 + kk + kg * 8]);
            #pragma unroll
            for (int mi = 0; mi < 8; ++mi) {
                bfx8 af = *reinterpret_cast<const bfx8*>(&As[(mi * 16 + lr) * 64 + kk + kg * 8]);
                acc[mi][0] = __builtin_amdgcn_mfma_f32_16x16x32_bf16(af, bv0, acc[mi][0], 0, 0, 0);
                acc[mi][1] = __builtin_amdgcn_mfma_f32_16x16x32_bf16(af, bv1, acc[mi][1], 0, 0, 0);
            }
        }
    }

    #pragma unroll
    for (int ni = 0; ni < 2; ++ni) {
        int b = n0 + wave * 32 + ni * 16 + lr;
        float zc = loadf(z_, b, f32);
        float zv = loadf(zb_, b, f32);
        #pragma unroll
        for (int mh = 0; mh < 2; ++mh) {
            #pragma unroll
            for (int r = 0; r < 4; ++r) {
                int j = j0 + mh * 16 + kg * 4 + r;
                float fp = acc[0 + mh][ni][r] + loadf(bias_, j, f32);
                float ip = acc[2 + mh][ni][r] + loadf(bias_, 1024 + j, f32);
                float op = acc[4 + mh][ni][r] + loadf(bias_, 2048 + j, f32);
                float gp = acc[6 + mh][ni][r] + loadf(bias_, 3072 + j, f32);
                float cc = loadf(c_, (size_t)j * 2048 + b, f32);
                float hh = loadf(h_, (size_t)j * 2048 + b, f32);
                float hn, cn;
                cell_math(fp, ip, op, gp, cc, hh, zc, zv, hn, cn);
                if (f32) {
                    ((float*)out_)[(size_t)j * 2048 + b] = hn;
                    ((float*)out_)[HB_ELEMS + (size_t)j * 2048 + b] = cn;
                } else {
                    ((unsigned short*)out_)[(size_t)j * 2048 + b] = f2b(hn);
                    ((unsigned short*)out_)[HB_ELEMS + (size_t)j * 2048 + b] = f2b(cn);
                }
            }
        }
    }
}

__global__ __launch_bounds__(256) void zrow_k(
    const void* __restrict__ Whh, const void* __restrict__ U11, const void* __restrict__ U21,
    const void* __restrict__ hb, const void* __restrict__ h, const void* __restrict__ ht,
    const void* __restrict__ z_, const void* __restrict__ bias_,
    void* __restrict__ out_, const int* __restrict__ flagp)
{
    const bool f32 = (*flagp != 0);
    int b = blockIdx.x * 256 + threadIdx.x;
    float a1 = 0.f, a2 = 0.f, a3 = 0.f;
    const size_t wrow = (size_t)4096 * 1024;
    for (int k = 0; k < 1024; ++k) {
        a1 += loadf(Whh, wrow + k, f32) * loadf(hb, (size_t)k * 2048 + b, f32);
        a2 += loadf(U11, wrow + k, f32) * loadf(h,  (size_t)k * 2048 + b, f32);
        a3 += loadf(U21, wrow + k, f32) * loadf(ht, (size_t)k * 2048 + b, f32);
    }
    float zc = loadf(z_, b, f32);
    float s = a1 + zc * (a2 + a3) + loadf(bias_, 4096, f32);
    float zh = (s + 1.0f) * 0.5f;
    zh = fminf(fmaxf(zh, 0.0f), 1.0f);
    float zn = (zh > 0.5f) ? 1.0f : 0.0f;
    if (f32) ((float*)out_)[2 * HB_ELEMS + b] = zn;
    else     ((unsigned short*)out_)[2 * HB_ELEMS + b] = f2b(zn);
}

__global__ __launch_bounds__(256) void fallback_k(
    const void* __restrict__ Whh, const void* __restrict__ U11, const void* __restrict__ U21,
    const void* __restrict__ hb, const void* __restrict__ h, const void* __restrict__ ht,
    const void* __restrict__ c_, const void* __restrict__ z_, const void* __restrict__ zb_,
    const void* __restrict__ bias_, void* __restrict__ out_, const int* __restrict__ flagp)
{
    const bool f32 = (*flagp != 0);
    int b = blockIdx.x * 256 + threadIdx.x;
    int j = blockIdx.y;
    float zc = loadf(z_, b, f32);
    float a[4] = {0.f, 0.f, 0.f, 0.f};
    for (int k = 0; k < 1024; ++k) {
        float xb = loadf(hb, (size_t)k * 2048 + b, f32);
        #pragma unroll
        for (int g = 0; g < 4; ++g)
            a[g] += loadf(Whh, (size_t)(g * 1024 + j) * 1024 + k, f32) * xb;
    }
    for (int k = 0; k < 1024; ++k) {
        float xh = zc * loadf(h, (size_t)k * 2048 + b, f32);
        #pragma unroll
        for (int g = 0; g < 4; ++g)
            a[g] += loadf(U11, (size_t)(g * 1024 + j) * 1024 + k, f32) * xh;
    }
    for (int k = 0; k < 1024; ++k) {
        float xt = zc * loadf(ht, (size_t)k * 2048 + b, f32);
        #pragma unroll
        for (int g = 0; g < 4; ++g)
            a[g] += loadf(U21, (size_t)(g * 1024 + j) * 1024 + k, f32) * xt;
    }
    float fp = a[0] + loadf(bias_, j, f32);
    float ip = a[1] + loadf(bias_, 1024 + j, f32);
    float op = a[2] + loadf(bias_, 2048 + j, f32);
    float gp = a[3] + loadf(bias_, 3072 + j, f32);
    float cc = loadf(c_, (size_t)j * 2048 + b, f32);
    float hh = loadf(h,  (size_t)j * 2048 + b, f32);
    float zv = loadf(zb_, b, f32);
    float hn, cn;
    cell_math(fp, ip, op, gp, cc, hh, zc, zv, hn, cn);
    if (f32) {
        ((float*)out_)[(size_t)j * 2048 + b] = hn;
        ((float*)out_)[HB_ELEMS + (size_t)j * 2048 + b] = cn;
    } else {
        ((unsigned short*)out_)[(size_t)j * 2048 + b] = f2b(hn);
        ((unsigned short*)out_)[HB_ELEMS + (size_t)j * 2048 + b] = f2b(cn);
    }
}

// ---------------------------------------------------------------------------
extern "C" void kernel_launch(void* const* d_in, const int* in_sizes, int n_in,
                              void* d_out, int out_size, void* d_ws, size_t ws_size,
                              hipStream_t stream)
{
    // setup_inputs order: c, h_bottom, h, h_top, z, z_bottom, W_hh, U_11, U_21, bias
    const void* c    = d_in[0];
    const void* hb   = d_in[1];
    const void* h    = d_in[2];
    const void* ht   = d_in[3];
    const void* z    = d_in[4];
    const void* zb   = d_in[5];
    const void* Whh  = d_in[6];
    const void* U11  = d_in[7];
    const void* U21  = d_in[8];
    const void* bias = d_in[9];

    int* flag = (int*)d_ws;
    unsigned short* BT = (unsigned short*)((char*)d_ws + 4096);
    const size_t bt_bytes = (size_t)2048 * 3072 * 2;                 // 12.58 MB
    float* pz = (float*)((char*)d_ws + 4096 + bt_bytes);
    const size_t pz_bytes = (size_t)96 * 2048 * 4;                   // 768 KB
    unsigned short* P = (unsigned short*)((char*)d_ws + 4096 + bt_bytes + pz_bytes);
    const size_t p_bytes = 3 * P_ELEMS * 2;                          // 50.3 MB (bf16)

    const size_t need_bt    = 4096 + bt_bytes;
    const size_t need_pz    = need_bt + pz_bytes;
    const size_t need_split = need_pz + p_bytes;                     // ~63.7 MB

    if (ws_size < 4) return;

    detect_k<<<1, 64, 0, stream>>>((const unsigned short*)Whh, flag);

    if (ws_size >= need_split) {
        // main path: 4 launches total
        build_plus<<<3072 + 96, 256, 0, stream>>>(hb, h, ht, z, Whh, U11, U21, BT, pz, flag);
        gemm_split<<<dim3(16, 32, 3), 256, 0, stream>>>(Whh, U11, U21, BT, P, flag);
        epilogue_plus<<<2048 + 8, 256, 0, stream>>>(P, pz, c, h, z, zb, bias, d_out, flag);
    } else if (ws_size >= need_bt) {
        build_bt_k<<<3072, 256, 0, stream>>>(hb, h, ht, z, BT, flag);
        gemm_fused<<<dim3(16, 32), 256, 0, stream>>>(Whh, U11, U21, BT,
                                                     c, h, z, zb, bias, d_out, flag);
        zrow_k<<<8, 256, 0, stream>>>(Whh, U11, U21, hb, h, ht, z, bias, d_out, flag);
    } else {
        fallback_k<<<dim3(8, 1024), 256, 0, stream>>>(Whh, U11, U21, hb, h, ht,
                                                      c, z, zb, bias, d_out, flag);
        zrow_k<<<8, 256, 0, stream>>>(Whh, U11, U21, hb, h, ht, z, bias, d_out, flag);
    }
}